// Round 6
// baseline (77.256 us; speedup 1.0000x reference)
//
#include <hip/hip_runtime.h>
#include <math.h>

#define NT  4096   // B*T tokens
#define DD  128
#define EE  256
#define CAP 2048   // per-expert pair-list capacity (observed max ~60)

// ---- K1: logits[t][e] = bg[e] + sum_d x[t][d]*Wg[d][e]; block0 zeroes cnt --
// 1024 blocks x 4 tokens. Thread e holds Wg column in VGPRs.
__global__ __launch_bounds__(256) void logits_kernel(
    const float* __restrict__ x, const float* __restrict__ Wg,
    const float* __restrict__ bg, float* __restrict__ logits,
    int* __restrict__ cnt)
{
    const int bid = blockIdx.x;
    // cnt is only read by the NEXT kernel (top2) — kernel boundary orders this.
    if (bid == 0) cnt[threadIdx.x] = 0;

    const int e  = threadIdx.x;
    const int t0 = bid * 4;
    float wreg[DD];
    #pragma unroll
    for (int d = 0; d < DD; ++d) wreg[d] = Wg[d * EE + e];
    const float be = bg[e];
    for (int tk = 0; tk < 4; tk += 2) {
        const float* xr0 = x + (size_t)(t0 + tk) * DD;
        const float* xr1 = xr0 + DD;
        float a0 = be, a1 = be;
        #pragma unroll
        for (int d0 = 0; d0 < DD; d0 += 4) {
            const float4 v0 = *reinterpret_cast<const float4*>(xr0 + d0);
            const float4 v1 = *reinterpret_cast<const float4*>(xr1 + d0);
            a0 = fmaf(v0.x, wreg[d0 + 0], a0);  a1 = fmaf(v1.x, wreg[d0 + 0], a1);
            a0 = fmaf(v0.y, wreg[d0 + 1], a0);  a1 = fmaf(v1.y, wreg[d0 + 1], a1);
            a0 = fmaf(v0.z, wreg[d0 + 2], a0);  a1 = fmaf(v1.z, wreg[d0 + 2], a1);
            a0 = fmaf(v0.w, wreg[d0 + 3], a0);  a1 = fmaf(v1.w, wreg[d0 + 3], a1);
        }
        logits[(size_t)(t0 + tk) * EE + e]     = a0;
        logits[(size_t)(t0 + tk + 1) * EE + e] = a1;
    }
}

// ---- K2: top-2 softmax weights + scatter pairs into per-expert lists -------
// One wave (64 lanes) per token, 4 tokens per block. (proven r3/r5)
__global__ __launch_bounds__(256) void top2_kernel(
    const float* __restrict__ logits, float2* __restrict__ w_out,
    int* __restrict__ cnt, int* __restrict__ plist)
{
    const int lane = threadIdx.x & 63;
    const int t    = blockIdx.x * 4 + (threadIdx.x >> 6);
    const float4 lg = *reinterpret_cast<const float4*>(logits + (size_t)t * EE + lane * 4);
    float v[4] = {lg.x, lg.y, lg.z, lg.w};

    // max + argmax (ties -> lowest index, matching jax top_k)
    float m = v[0]; int mi = lane * 4;
    #pragma unroll
    for (int j = 1; j < 4; ++j)
        if (v[j] > m) { m = v[j]; mi = lane * 4 + j; }
    #pragma unroll
    for (int s = 32; s; s >>= 1) {
        const float om = __shfl_xor(m, s);
        const int   oi = __shfl_xor(mi, s);
        if (om > m || (om == m && oi < mi)) { m = om; mi = oi; }
    }

    // softmax denominator
    float ssum = 0.0f;
    #pragma unroll
    for (int j = 0; j < 4; ++j) ssum += __expf(v[j] - m);
    #pragma unroll
    for (int s = 32; s; s >>= 1) ssum += __shfl_xor(ssum, s);

    // second max (exclude mi)
    float m2 = -INFINITY; int mi2 = 0;
    #pragma unroll
    for (int j = 0; j < 4; ++j) {
        const int ei = lane * 4 + j;
        if (ei != mi && v[j] > m2) { m2 = v[j]; mi2 = ei; }
    }
    #pragma unroll
    for (int s = 32; s; s >>= 1) {
        const float om = __shfl_xor(m2, s);
        const int   oi = __shfl_xor(mi2, s);
        if (om > m2 || (om == m2 && oi < mi2)) { m2 = om; mi2 = oi; }
    }

    if (lane == 0) {
        const float p1 = 1.0f / ssum;
        const float p2 = __expf(m2 - m) / ssum;
        const float den = p1 + p2 + 1e-6f;
        w_out[t] = make_float2(p1 / den, p2 / den);
        const int pos1 = atomicAdd(&cnt[mi], 1);
        if (pos1 < CAP) plist[mi * CAP + pos1] = t * 2;       // slot 0
        const int pos2 = atomicAdd(&cnt[mi2], 1);
        if (pos2 < CAP) plist[mi2 * CAP + pos2] = t * 2 + 1;  // slot 1
    }
}

// ---- K3: expert matvecs, 8 blocks/expert, 4-way pair ILP, XCD swizzle ------
__global__ __launch_bounds__(128) void expert_kernel(
    const float* __restrict__ x, const float* __restrict__ ew,
    const int* __restrict__ cnt, const int* __restrict__ plist,
    float* __restrict__ ybuf)
{
    // bijective swizzle: 256 consecutive logical wgs (32 experts) per XCD
    const int wg = (blockIdx.x & 7) * 256 + (blockIdx.x >> 3);
    const int e  = wg >> 3;
    const int j  = wg & 7;
    int n = cnt[e];
    if (n > CAP) n = CAP;
    if (j >= n) return;

    const int o = threadIdx.x;
    const float* W = ew + (size_t)e * DD * DD;
    float wreg[DD];
    #pragma unroll
    for (int d = 0; d < DD; ++d) wreg[d] = W[d * DD + o];
    const int* pl = plist + e * CAP;

    for (int base = j; base < n; base += 32) {
        const int i1 = base + 8, i2 = base + 16, i3 = base + 24;
        const int f0 = pl[base];
        const int f1 = (i1 < n) ? pl[i1] : f0;
        const int f2 = (i2 < n) ? pl[i2] : f0;
        const int f3 = (i3 < n) ? pl[i3] : f0;
        const float* x0 = x + (size_t)(f0 >> 1) * DD;
        const float* x1 = x + (size_t)(f1 >> 1) * DD;
        const float* x2 = x + (size_t)(f2 >> 1) * DD;
        const float* x3 = x + (size_t)(f3 >> 1) * DD;
        float acc0 = 0.0f, acc1 = 0.0f, acc2 = 0.0f, acc3 = 0.0f;
        #pragma unroll
        for (int d0 = 0; d0 < DD; d0 += 4) {
            const float4 v0 = *reinterpret_cast<const float4*>(x0 + d0);
            const float4 v1 = *reinterpret_cast<const float4*>(x1 + d0);
            const float4 v2 = *reinterpret_cast<const float4*>(x2 + d0);
            const float4 v3 = *reinterpret_cast<const float4*>(x3 + d0);
            const float w0 = wreg[d0 + 0], w1_ = wreg[d0 + 1];
            const float w2_ = wreg[d0 + 2], w3_ = wreg[d0 + 3];
            acc0 = fmaf(v0.x, w0, acc0);  acc1 = fmaf(v1.x, w0, acc1);
            acc2 = fmaf(v2.x, w0, acc2);  acc3 = fmaf(v3.x, w0, acc3);
            acc0 = fmaf(v0.y, w1_, acc0); acc1 = fmaf(v1.y, w1_, acc1);
            acc2 = fmaf(v2.y, w1_, acc2); acc3 = fmaf(v3.y, w1_, acc3);
            acc0 = fmaf(v0.z, w2_, acc0); acc1 = fmaf(v1.z, w2_, acc1);
            acc2 = fmaf(v2.z, w2_, acc2); acc3 = fmaf(v3.z, w2_, acc3);
            acc0 = fmaf(v0.w, w3_, acc0); acc1 = fmaf(v1.w, w3_, acc1);
            acc2 = fmaf(v2.w, w3_, acc2); acc3 = fmaf(v3.w, w3_, acc3);
        }
        ybuf[(size_t)f0 * DD + o] = acc0;
        if (i1 < n) ybuf[(size_t)f1 * DD + o] = acc1;
        if (i2 < n) ybuf[(size_t)f2 * DD + o] = acc2;
        if (i3 < n) ybuf[(size_t)f3 * DD + o] = acc3;
    }
}

// ---- K4: mixed + SwiGLU + variance consensus (proven r3/r5 inner code) -----
// 1024 blocks x 4 tokens.
__global__ __launch_bounds__(256) void swiglu_kernel(
    const float* __restrict__ ybuf, const float2* __restrict__ ww,
    const float* __restrict__ w1, const float* __restrict__ b1,
    const float* __restrict__ w2, const float* __restrict__ b2,
    float* __restrict__ out_avg, float* __restrict__ out_cons)
{
    const int o     = threadIdx.x & 127;
    const int which = threadIdx.x >> 7;
    const int t0    = blockIdx.x * 4;
    const float* Wc  = which ? w2 : w1;
    const float bias = which ? b2[o] : b1[o];
    float wreg[DD];
    #pragma unroll
    for (int d = 0; d < DD; ++d) wreg[d] = Wc[d * DD + o];

    __shared__ float ms[DD];
    __shared__ float hs[DD];
    __shared__ float vred[2];

    for (int tk = 0; tk < 4; ++tk) {
        const int t = t0 + tk;
        const float2 w = ww[t];
        const float ya = ybuf[(size_t)(2 * t) * DD + o];
        const float yb = ybuf[(size_t)(2 * t + 1) * DD + o];
        const float mx = w.x * ya + w.y * yb;
        if (!which) ms[o] = mx;
        __syncthreads();

        float acc = bias;
        #pragma unroll
        for (int d0 = 0; d0 < DD; d0 += 4) {
            const float4 mv = *reinterpret_cast<const float4*>(ms + d0);
            acc = fmaf(mv.x, wreg[d0 + 0], acc);
            acc = fmaf(mv.y, wreg[d0 + 1], acc);
            acc = fmaf(mv.z, wreg[d0 + 2], acc);
            acc = fmaf(mv.w, wreg[d0 + 3], acc);
        }
        if (which) hs[o] = acc;
        __syncthreads();

        if (!which) {
            const float g   = acc, hv = hs[o];
            const float sig = 1.0f / (1.0f + __expf(-g));
            const float wavg = g * sig * hv;
            out_avg[(size_t)t * DD + o] = wavg;
            const float da = ya - wavg, db = yb - wavg;
            float v = w.x * da * da + w.y * db * db;
            #pragma unroll
            for (int s = 32; s; s >>= 1) v += __shfl_down(v, s);
            if ((o & 63) == 0) vred[o >> 6] = v;
        }
        __syncthreads();
        if (threadIdx.x == 0)
            out_cons[t] = __expf(-(vred[0] + vred[1]) * (1.0f / DD));
        __syncthreads();
    }
}

extern "C" void kernel_launch(void* const* d_in, const int* in_sizes, int n_in,
                              void* d_out, int out_size, void* d_ws, size_t ws_size,
                              hipStream_t stream) {
    const float* x   = (const float*)d_in[0];
    const float* Wg  = (const float*)d_in[1];
    const float* bg  = (const float*)d_in[2];
    const float* ew  = (const float*)d_in[3];
    const float* w1  = (const float*)d_in[4];
    const float* b1  = (const float*)d_in[5];
    const float* w2  = (const float*)d_in[6];
    const float* b2  = (const float*)d_in[7];

    float* out_avg  = (float*)d_out;              // [NT, D]
    float* out_cons = out_avg + (size_t)NT * DD;  // [NT]

    // ws layout: logits 4MB (aliased by ybuf) | ww 32KB | cnt 32KB(pad) | plist 2MB
    char* ws = (char*)d_ws;
    float*  logits = (float*)ws;                           // [NT,EE]
    float*  ybuf   = logits;                               // [NT*2,DD] alias
    float2* wwp    = (float2*)(ws + 4 * 1024 * 1024);
    int*    cnt    = (int*)   (ws + 4 * 1024 * 1024 + 32 * 1024);
    int*    plist  = (int*)   (ws + 4 * 1024 * 1024 + 64 * 1024);  // [EE,CAP]

    logits_kernel<<<NT / 4, 256, 0, stream>>>(x, Wg, bg, logits, cnt);
    top2_kernel  <<<NT / 4, 256, 0, stream>>>(logits, wwp, cnt, plist);
    expert_kernel<<<EE * 8, 128, 0, stream>>>(x, ew, cnt, plist, ybuf);
    swiglu_kernel<<<NT / 4, 256, 0, stream>>>(ybuf, wwp, w1, b1, w2, b2,
                                              out_avg, out_cons);
}